// Round 1
// baseline (558.611 us; speedup 1.0000x reference)
//
#include <hip/hip_runtime.h>

#define B_ 16
#define NC 1024
#define NF 4096
#define CIN 256
#define CSKIP 128
#define CHID 256
#define MTOT (B_ * NF)   // 65536
#define EPS_ 1e-16f

// ---------------- kNN top-3 + inverse-d2 weights ----------------
__global__ __launch_bounds__(256) void knn_kernel(
    const float* __restrict__ pos, const float* __restrict__ pos_skip,
    int* __restrict__ idx3, float* __restrict__ w3)
{
    __shared__ float cx[NC], cy[NC], cz[NC];
    const int b   = blockIdx.x >> 4;   // batch
    const int blk = blockIdx.x & 15;
    const float* cp = pos + (size_t)b * NC * 3;
    for (int i = threadIdx.x; i < NC; i += 256) {
        cx[i] = cp[i * 3 + 0];
        cy[i] = cp[i * 3 + 1];
        cz[i] = cp[i * 3 + 2];
    }
    __syncthreads();

    const int f = b * NF + blk * 256 + threadIdx.x;  // global fine index
    const float px = pos_skip[f * 3 + 0];
    const float py = pos_skip[f * 3 + 1];
    const float pz = pos_skip[f * 3 + 2];

    float d0 = 3.4e38f, d1 = 3.4e38f, d2 = 3.4e38f;
    int   i0 = 0, i1 = 0, i2 = 0;
    for (int j = 0; j < NC; ++j) {
        float dx = px - cx[j], dy = py - cy[j], dz = pz - cz[j];
        float d = dx * dx + dy * dy + dz * dz;
        if (d < d2) {
            if (d < d1) {
                d2 = d1; i2 = i1;
                if (d < d0) { d1 = d0; i1 = i0; d0 = d; i0 = j; }
                else        { d1 = d;  i1 = j; }
            } else { d2 = d; i2 = j; }
        }
    }
    float w0 = 1.0f / fmaxf(d0, EPS_);
    float w1 = 1.0f / fmaxf(d1, EPS_);
    float w2 = 1.0f / fmaxf(d2, EPS_);
    float inv = 1.0f / (w0 + w1 + w2);
    idx3[f * 3 + 0] = b * NC + i0;   // store GLOBAL coarse row
    idx3[f * 3 + 1] = b * NC + i1;
    idx3[f * 3 + 2] = b * NC + i2;
    w3[f * 3 + 0] = w0 * inv;
    w3[f * 3 + 1] = w1 * inv;
    w3[f * 3 + 2] = w2 * inv;
}

// ---------------- weighted gather: interp[m][c] ----------------
__global__ __launch_bounds__(256) void interp_kernel(
    const float* __restrict__ x, const int* __restrict__ idx3,
    const float* __restrict__ w3, float* __restrict__ interp)
{
    const int lr = threadIdx.x >> 6;          // 0..3 row within group
    const int c4 = (threadIdx.x & 63) << 2;   // channel (float4 granular)
    const int base = blockIdx.x * 16;
#pragma unroll
    for (int rr = 0; rr < 4; ++rr) {
        const int m = base + rr * 4 + lr;
        const int i0 = idx3[m * 3 + 0], i1 = idx3[m * 3 + 1], i2 = idx3[m * 3 + 2];
        const float w0 = w3[m * 3 + 0], w1 = w3[m * 3 + 1], w2 = w3[m * 3 + 2];
        float4 a = *(const float4*)&x[(size_t)i0 * CIN + c4];
        float4 b = *(const float4*)&x[(size_t)i1 * CIN + c4];
        float4 c = *(const float4*)&x[(size_t)i2 * CIN + c4];
        float4 o;
        o.x = w0 * a.x + w1 * b.x + w2 * c.x;
        o.y = w0 * a.y + w1 * b.y + w2 * c.y;
        o.z = w0 * a.z + w1 * b.z + w2 * c.z;
        o.w = w0 * a.w + w1 * b.w + w2 * c.w;
        *(float4*)&interp[(size_t)m * CIN + c4] = o;
    }
}

// ---------------- f32 tiled GEMM + bias + ReLU ----------------
// C[M x 256] = relu(A @ W + bias); A split: cols [0,CA0) from A0, rest from A1.
template <int K, int CA0>
__global__ __launch_bounds__(256) void gemm_bias_relu(
    const float* __restrict__ A0, int lda0,
    const float* __restrict__ A1, int lda1,
    const float* __restrict__ W, const float* __restrict__ bias,
    float* __restrict__ C)
{
    constexpr int BM = 128, BN = 128, BK = 16;
    __shared__ float As[BK][BM];
    __shared__ float Bs[BK][BN];
    const int tid = threadIdx.x;
    const int m0 = blockIdx.x * BM;
    const int n0 = blockIdx.y * BN;
    const int ty = tid >> 4, tx = tid & 15;
    const int am = tid >> 2, ak = (tid & 3) << 2;   // A-tile load coords
    const int bk = tid >> 5, bn4 = (tid & 31) << 2; // B-tile load coords

    float acc[8][8] = {};

    for (int k0 = 0; k0 < K; k0 += BK) {
#pragma unroll
        for (int r = 0; r < 2; ++r) {
            const int m = am + r * 64;
            const int kk = k0 + ak;
            float4 v;
            if (CA0 >= K || kk < CA0)
                v = *(const float4*)&A0[(size_t)(m0 + m) * lda0 + kk];
            else
                v = *(const float4*)&A1[(size_t)(m0 + m) * lda1 + (kk - CA0)];
            As[ak + 0][m] = v.x; As[ak + 1][m] = v.y;
            As[ak + 2][m] = v.z; As[ak + 3][m] = v.w;
        }
#pragma unroll
        for (int r = 0; r < 2; ++r) {
            const int kk = bk + r * 8;
            *(float4*)&Bs[kk][bn4] = *(const float4*)&W[(size_t)(k0 + kk) * 256 + n0 + bn4];
        }
        __syncthreads();
#pragma unroll
        for (int k = 0; k < BK; ++k) {
            float a[8], bf[8];
            *(float4*)&a[0]  = *(const float4*)&As[k][ty * 4];
            *(float4*)&a[4]  = *(const float4*)&As[k][ty * 4 + 64];
            *(float4*)&bf[0] = *(const float4*)&Bs[k][tx * 4];
            *(float4*)&bf[4] = *(const float4*)&Bs[k][tx * 4 + 64];
#pragma unroll
            for (int i = 0; i < 8; ++i)
#pragma unroll
                for (int j = 0; j < 8; ++j)
                    acc[i][j] = fmaf(a[i], bf[j], acc[i][j]);
        }
        __syncthreads();
    }
#pragma unroll
    for (int i = 0; i < 8; ++i) {
        const int row = m0 + ty * 4 + (i & 3) + ((i >> 2) << 6);
#pragma unroll
        for (int h = 0; h < 2; ++h) {
            const int col = n0 + tx * 4 + (h << 6);
            float4 v;
            v.x = fmaxf(acc[i][h * 4 + 0] + bias[col + 0], 0.0f);
            v.y = fmaxf(acc[i][h * 4 + 1] + bias[col + 1], 0.0f);
            v.z = fmaxf(acc[i][h * 4 + 2] + bias[col + 2], 0.0f);
            v.w = fmaxf(acc[i][h * 4 + 3] + bias[col + 3], 0.0f);
            *(float4*)&C[(size_t)row * 256 + col] = v;
        }
    }
}

// ---------------- tail: pos_skip passthrough + batch_skip as float ----------------
__global__ __launch_bounds__(256) void copy_tail_kernel(
    const float* __restrict__ pos_skip, const int* __restrict__ batch_skip,
    float* __restrict__ out)
{
    const int i = blockIdx.x * 256 + threadIdx.x;
    const int npos = MTOT * 3;
    if (i < npos)               out[i] = pos_skip[i];
    else if (i < npos + MTOT)   out[i] = (float)batch_skip[i - npos];
}

extern "C" void kernel_launch(void* const* d_in, const int* in_sizes, int n_in,
                              void* d_out, int out_size, void* d_ws, size_t ws_size,
                              hipStream_t stream)
{
    const float* x        = (const float*)d_in[0];
    const float* pos      = (const float*)d_in[1];
    const float* x_skip   = (const float*)d_in[2];
    const float* pos_skip = (const float*)d_in[3];
    const float* W1       = (const float*)d_in[4];
    const float* b1       = (const float*)d_in[5];
    const float* W2       = (const float*)d_in[6];
    const float* b2       = (const float*)d_in[7];
    const int*   batch_skip = (const int*)d_in[9];
    float* out = (float*)d_out;

    char* ws = (char*)d_ws;
    int*   idx3   = (int*)ws;                                    // 768 KB
    float* w3     = (float*)(ws + (1u << 20));                   // 768 KB
    float* interp = (float*)(ws + (2u << 20));                   // 64 MB
    float* h1     = (float*)(ws + (2u << 20) + (size_t)MTOT * CHID * 4); // 64 MB

    knn_kernel<<<256, 256, 0, stream>>>(pos, pos_skip, idx3, w3);
    interp_kernel<<<MTOT / 16, 256, 0, stream>>>(x, idx3, w3, interp);

    dim3 g(MTOT / 128, 2);
    gemm_bias_relu<384, 256><<<g, 256, 0, stream>>>(interp, CIN, x_skip, CSKIP, W1, b1, h1);
    gemm_bias_relu<256, 256><<<g, 256, 0, stream>>>(h1, CHID, nullptr, 0, W2, b2, out);

    copy_tail_kernel<<<1024, 256, 0, stream>>>(pos_skip, batch_skip,
                                               out + (size_t)MTOT * CHID);
}

// Round 2
// 314.264 us; speedup vs baseline: 1.7775x; 1.7775x over previous
//
#include <hip/hip_runtime.h>

#define B_ 16
#define NC 1024
#define NF 4096
#define CIN 256
#define CSKIP 128
#define CHID 256
#define MTOT (B_ * NF)   // 65536
#define EPS_ 1e-16f

typedef _Float16 f16;
typedef __attribute__((ext_vector_type(8))) _Float16 f16x8;
typedef __attribute__((ext_vector_type(2))) _Float16 f16x2;
typedef __attribute__((ext_vector_type(4))) float f32x4;

// ---------------- kNN top-3 + inverse-d2 weights ----------------
__global__ __launch_bounds__(256) void knn_kernel(
    const float* __restrict__ pos, const float* __restrict__ pos_skip,
    int* __restrict__ idx3, float* __restrict__ w3)
{
    __shared__ float cx[NC], cy[NC], cz[NC];
    const int b   = blockIdx.x >> 4;   // batch
    const int blk = blockIdx.x & 15;
    const float* cp = pos + (size_t)b * NC * 3;
    for (int i = threadIdx.x; i < NC; i += 256) {
        cx[i] = cp[i * 3 + 0];
        cy[i] = cp[i * 3 + 1];
        cz[i] = cp[i * 3 + 2];
    }
    __syncthreads();

    const int f = b * NF + blk * 256 + threadIdx.x;  // global fine index
    const float px = pos_skip[f * 3 + 0];
    const float py = pos_skip[f * 3 + 1];
    const float pz = pos_skip[f * 3 + 2];

    float d0 = 3.4e38f, d1 = 3.4e38f, d2 = 3.4e38f;
    int   i0 = 0, i1 = 0, i2 = 0;
    for (int j = 0; j < NC; ++j) {
        float dx = px - cx[j], dy = py - cy[j], dz = pz - cz[j];
        float d = dx * dx + dy * dy + dz * dz;
        if (d < d2) {
            if (d < d1) {
                d2 = d1; i2 = i1;
                if (d < d0) { d1 = d0; i1 = i0; d0 = d; i0 = j; }
                else        { d1 = d;  i1 = j; }
            } else { d2 = d; i2 = j; }
        }
    }
    float w0 = 1.0f / fmaxf(d0, EPS_);
    float w1 = 1.0f / fmaxf(d1, EPS_);
    float w2 = 1.0f / fmaxf(d2, EPS_);
    float inv = 1.0f / (w0 + w1 + w2);
    idx3[f * 3 + 0] = b * NC + i0;   // GLOBAL coarse row
    idx3[f * 3 + 1] = b * NC + i1;
    idx3[f * 3 + 2] = b * NC + i2;
    w3[f * 3 + 0] = w0 * inv;
    w3[f * 3 + 1] = w1 * inv;
    w3[f * 3 + 2] = w2 * inv;
}

// ---------------- fused interp-gather + x_skip concat -> A1 f16 [M][384] ----------------
__global__ __launch_bounds__(192) void prep_kernel(
    const float* __restrict__ x, const float* __restrict__ x_skip,
    const int* __restrict__ idx3, const float* __restrict__ w3,
    f16* __restrict__ A1)
{
    const int m = blockIdx.x;
    const int t = threadIdx.x;
    if (t < 128) {
        const int c = t * 2;
        const int i0 = idx3[m * 3 + 0], i1 = idx3[m * 3 + 1], i2 = idx3[m * 3 + 2];
        const float w0 = w3[m * 3 + 0], w1 = w3[m * 3 + 1], w2 = w3[m * 3 + 2];
        float2 a = *(const float2*)&x[(size_t)i0 * CIN + c];
        float2 b = *(const float2*)&x[(size_t)i1 * CIN + c];
        float2 d = *(const float2*)&x[(size_t)i2 * CIN + c];
        f16x2 o;
        o.x = (f16)(w0 * a.x + w1 * b.x + w2 * d.x);
        o.y = (f16)(w0 * a.y + w1 * b.y + w2 * d.y);
        *(f16x2*)&A1[(size_t)m * 384 + c] = o;
    } else {
        const int c = (t - 128) * 2;
        float2 v = *(const float2*)&x_skip[(size_t)m * CSKIP + c];
        f16x2 o;
        o.x = (f16)v.x;
        o.y = (f16)v.y;
        *(f16x2*)&A1[(size_t)m * 384 + 256 + c] = o;
    }
}

// ---------------- weight transpose + f16 convert: Wt[n][k] = (f16)W[k][n] ----------------
__global__ __launch_bounds__(256) void wconv_kernel(
    const float* __restrict__ W1, const float* __restrict__ W2,
    f16* __restrict__ W1t, f16* __restrict__ W2t)
{
    const int t = blockIdx.x * 256 + threadIdx.x;
    if (t < 384 * 256) {
        const int k = t >> 8, n = t & 255;
        W1t[n * 384 + k] = (f16)W1[t];
    } else if (t < 384 * 256 + 256 * 256) {
        const int u = t - 384 * 256;
        const int k = u >> 8, n = u & 255;
        W2t[n * 256 + k] = (f16)W2[u];
    }
}

// ---------------- async global->LDS, 16B per lane, linear dest ----------------
__device__ __forceinline__ void gload16(const void* g, void* l)
{
    __builtin_amdgcn_global_load_lds(
        (const __attribute__((address_space(1))) unsigned int*)g,
        (__attribute__((address_space(3))) unsigned int*)l, 16, 0, 0);
}

// ---------------- f16 MFMA GEMM: C[M x 256] = act(A[M x K] @ Bt[256 x K]^T + bias) ----------------
// 128x128 tile, BK=64, 4 waves (2x2), each wave 64x64 via 4x4 16x16x32 fragments.
// LDS tiles linear [128 rows][64 k] f16 (128 B/row); XOR swizzle: 16B-slot ^= (row&7),
// applied on the inverse-swizzled global SOURCE at staging and on the ds_read address.
template <int K, bool OUT_F16>
__global__ __launch_bounds__(256) void gemm_f16_mfma(
    const f16* __restrict__ A, const f16* __restrict__ Bt,
    const float* __restrict__ bias, void* __restrict__ Cout)
{
    __shared__ f16 As[128 * 64];   // 16 KB
    __shared__ f16 Bs[128 * 64];   // 16 KB
    const int tid  = threadIdx.x;
    const int lane = tid & 63;
    const int wid  = tid >> 6;
    const int wr   = wid >> 1, wc = wid & 1;
    const int m0 = blockIdx.x * 128;
    const int n0 = blockIdx.y * 128;

    // staging coords: chunk c = wid*4 + r covers LDS bytes [c*1024, c*1024+1024)
    // row = c*8 + (lane>>3); 16B slot within row = lane&7
    // slot s holds source k-chunk (s ^ (row&7))  [inverse swizzle on source]
    const int srow_l = lane >> 3;                       // row offset within chunk
    const int kch    = (lane & 7) ^ ((lane >> 3) & 7);  // source k-chunk (16B = 8 f16)

    f32x4 acc[4][4] = {};

    for (int k0 = 0; k0 < K; k0 += 64) {
#pragma unroll
        for (int r = 0; r < 4; ++r) {
            const int c = (wid << 2) + r;
            const int row = (c << 3) + srow_l;
            gload16(A  + (size_t)(m0 + row) * K + k0 + kch * 8,
                    (char*)As + (c << 10));
            gload16(Bt + (size_t)(n0 + row) * K + k0 + kch * 8,
                    (char*)Bs + (c << 10));
        }
        __syncthreads();   // compiler drains vmcnt(0) before s_barrier

#pragma unroll
        for (int h = 0; h < 2; ++h) {
            f16x8 aF[4], bF[4];
#pragma unroll
            for (int m = 0; m < 4; ++m) {
                const int row  = wr * 64 + m * 16 + (lane & 15);
                const int kg   = (h << 2) + (lane >> 4);       // 0..7
                const int slot = kg ^ (row & 7);
                aF[m] = *(const f16x8*)((const char*)As + row * 128 + slot * 16);
            }
#pragma unroll
            for (int n = 0; n < 4; ++n) {
                const int row  = wc * 64 + n * 16 + (lane & 15);
                const int kg   = (h << 2) + (lane >> 4);
                const int slot = kg ^ (row & 7);
                bF[n] = *(const f16x8*)((const char*)Bs + row * 128 + slot * 16);
            }
#pragma unroll
            for (int m = 0; m < 4; ++m)
#pragma unroll
                for (int n = 0; n < 4; ++n)
                    acc[m][n] = __builtin_amdgcn_mfma_f32_16x16x32_f16(
                        aF[m], bF[n], acc[m][n], 0, 0, 0);
        }
        __syncthreads();
    }

    // epilogue: C/D layout col=lane&15, row=(lane>>4)*4+reg  [m89]
#pragma unroll
    for (int m = 0; m < 4; ++m) {
#pragma unroll
        for (int n = 0; n < 4; ++n) {
            const int col = n0 + wc * 64 + n * 16 + (lane & 15);
            const float bv = bias[col];
#pragma unroll
            for (int r = 0; r < 4; ++r) {
                const int row = m0 + wr * 64 + m * 16 + ((lane >> 4) << 2) + r;
                const float v = fmaxf(acc[m][n][r] + bv, 0.0f);
                if (OUT_F16)
                    ((f16*)Cout)[(size_t)row * 256 + col] = (f16)v;
                else
                    ((float*)Cout)[(size_t)row * 256 + col] = v;
            }
        }
    }
}

// ---------------- tail: pos_skip passthrough + batch_skip as float ----------------
__global__ __launch_bounds__(256) void copy_tail_kernel(
    const float* __restrict__ pos_skip, const int* __restrict__ batch_skip,
    float* __restrict__ out)
{
    const int i = blockIdx.x * 256 + threadIdx.x;
    const int npos = MTOT * 3;
    if (i < npos)               out[i] = pos_skip[i];
    else if (i < npos + MTOT)   out[i] = (float)batch_skip[i - npos];
}

extern "C" void kernel_launch(void* const* d_in, const int* in_sizes, int n_in,
                              void* d_out, int out_size, void* d_ws, size_t ws_size,
                              hipStream_t stream)
{
    const float* x        = (const float*)d_in[0];
    const float* pos      = (const float*)d_in[1];
    const float* x_skip   = (const float*)d_in[2];
    const float* pos_skip = (const float*)d_in[3];
    const float* W1       = (const float*)d_in[4];
    const float* b1       = (const float*)d_in[5];
    const float* W2       = (const float*)d_in[6];
    const float* b2       = (const float*)d_in[7];
    const int*   batch_skip = (const int*)d_in[9];
    float* out = (float*)d_out;

    char* ws = (char*)d_ws;
    int*   idx3 = (int*)ws;                          // 768 KB
    float* w3   = (float*)(ws + (1u << 20));         // 768 KB
    f16*   W1t  = (f16*)(ws + (2u << 20));           // 192 KB
    f16*   W2t  = (f16*)(ws + (2u << 20) + (512u << 10)); // 128 KB
    f16*   A1   = (f16*)(ws + (4u << 20));           // 48 MB
    f16*   h1   = (f16*)(ws + (56u << 20));          // 32 MB

    knn_kernel<<<256, 256, 0, stream>>>(pos, pos_skip, idx3, w3);
    wconv_kernel<<<640, 256, 0, stream>>>(W1, W2, W1t, W2t);
    prep_kernel<<<MTOT, 192, 0, stream>>>(x, x_skip, idx3, w3, A1);

    dim3 g(MTOT / 128, 2);
    gemm_f16_mfma<384, true ><<<g, 256, 0, stream>>>(A1, W1t, b1, h1);
    gemm_f16_mfma<256, false><<<g, 256, 0, stream>>>(h1, W2t, b2, out);

    copy_tail_kernel<<<1024, 256, 0, stream>>>(pos_skip, batch_skip,
                                               out + (size_t)MTOT * CHID);
}

// Round 4
// 227.744 us; speedup vs baseline: 2.4528x; 1.3799x over previous
//
#include <hip/hip_runtime.h>

#define B_ 16
#define NC 1024
#define NF 4096
#define CIN 256
#define CSKIP 128
#define CHID 256
#define MTOT (B_ * NF)   // 65536
#define EPS_ 1e-16f

typedef _Float16 f16;
typedef __attribute__((ext_vector_type(8))) _Float16 f16x8;
typedef __attribute__((ext_vector_type(4))) _Float16 f16x4;
typedef __attribute__((ext_vector_type(2))) _Float16 f16x2;
typedef __attribute__((ext_vector_type(4))) float f32x4;

// ---------------- kNN top-3, coarse dim split 4x for occupancy ----------------
// block = 256 thr = 64 fine points x 4 coarse-quarters; 1024 blocks total
// -> 4 waves/SIMD (was 1). Coarse pos packed float4 in LDS; wave-uniform
// broadcast ds_read_b128 per candidate.
__global__ __launch_bounds__(256) void knn_kernel(
    const float* __restrict__ pos, const float* __restrict__ pos_skip,
    int* __restrict__ idx3, float* __restrict__ w3)
{
    __shared__ float4 cpos[NC];          // 16 KB
    __shared__ float  cd[64 * 12];       // 3 KB
    __shared__ int    ci[64 * 12];       // 3 KB

    const int b  = blockIdx.x >> 6;          // batch (64 blocks per batch)
    const int fb = blockIdx.x & 63;          // fine 64-group within batch
    const float* cp = pos + (size_t)b * NC * 3;
    for (int i = threadIdx.x; i < NC; i += 256)
        cpos[i] = make_float4(cp[i * 3], cp[i * 3 + 1], cp[i * 3 + 2], 0.0f);
    __syncthreads();

    const int fl = threadIdx.x & 63;
    const int q  = threadIdx.x >> 6;
    const int f  = b * NF + fb * 64 + fl;    // global fine index
    const float px = pos_skip[f * 3 + 0];
    const float py = pos_skip[f * 3 + 1];
    const float pz = pos_skip[f * 3 + 2];

    float d0 = 3.4e38f, d1 = 3.4e38f, d2 = 3.4e38f;
    int   i0 = 0, i1 = 0, i2 = 0;
    const int jbase = q << 8;
#pragma unroll 4
    for (int jj = 0; jj < 256; ++jj) {
        const int j = jbase + jj;
        float4 c = cpos[j];
        float dx = px - c.x, dy = py - c.y, dz = pz - c.z;
        float d = fmaf(dx, dx, fmaf(dy, dy, dz * dz));
        if (d < d2) {
            if (d < d1) {
                d2 = d1; i2 = i1;
                if (d < d0) { d1 = d0; i1 = i0; d0 = d; i0 = j; }
                else        { d1 = d;  i1 = j; }
            } else { d2 = d; i2 = j; }
        }
    }
    const int cb = fl * 12 + q * 3;
    cd[cb + 0] = d0; cd[cb + 1] = d1; cd[cb + 2] = d2;
    ci[cb + 0] = i0; ci[cb + 1] = i1; ci[cb + 2] = i2;
    __syncthreads();

    // wave 0 merges: quarters in ascending-index order, strict < insert
    // exactly reproduces top_k's lowest-index tie-breaking.
    if (threadIdx.x < 64) {
        float e0 = 3.4e38f, e1 = 3.4e38f, e2 = 3.4e38f;
        int   j0 = 0, j1 = 0, j2 = 0;
#pragma unroll
        for (int s = 0; s < 12; ++s) {
            const float d = cd[fl * 12 + s];
            const int   j = ci[fl * 12 + s];
            if (d < e2) {
                if (d < e1) {
                    e2 = e1; j2 = j1;
                    if (d < e0) { e1 = e0; j1 = j0; e0 = d; j0 = j; }
                    else        { e1 = d;  j1 = j; }
                } else { e2 = d; j2 = j; }
            }
        }
        float w0 = 1.0f / fmaxf(e0, EPS_);
        float w1 = 1.0f / fmaxf(e1, EPS_);
        float w2 = 1.0f / fmaxf(e2, EPS_);
        float inv = 1.0f / (w0 + w1 + w2);
        idx3[f * 3 + 0] = b * NC + j0;
        idx3[f * 3 + 1] = b * NC + j1;
        idx3[f * 3 + 2] = b * NC + j2;
        w3[f * 3 + 0] = w0 * inv;
        w3[f * 3 + 1] = w1 * inv;
        w3[f * 3 + 2] = w2 * inv;
    }
}

// ---------------- fused interp-gather + x_skip concat -> A1 f16 [M][384] ----------------
// 4 rows per 256-thread block; one wave per row. Lane: 4 interp ch (float4
// gather x3) + 2 skip ch.
__global__ __launch_bounds__(256) void prep_kernel(
    const float* __restrict__ x, const float* __restrict__ x_skip,
    const int* __restrict__ idx3, const float* __restrict__ w3,
    f16* __restrict__ A1)
{
    const int w = threadIdx.x >> 6, l = threadIdx.x & 63;
    const int m = blockIdx.x * 4 + w;
    const int i0 = idx3[m * 3 + 0], i1 = idx3[m * 3 + 1], i2 = idx3[m * 3 + 2];
    const float w0 = w3[m * 3 + 0], w1 = w3[m * 3 + 1], w2 = w3[m * 3 + 2];
    const int c = l * 4;
    float4 a = *(const float4*)&x[(size_t)i0 * CIN + c];
    float4 b = *(const float4*)&x[(size_t)i1 * CIN + c];
    float4 d = *(const float4*)&x[(size_t)i2 * CIN + c];
    f16x4 o;
    o.x = (f16)(w0 * a.x + w1 * b.x + w2 * d.x);
    o.y = (f16)(w0 * a.y + w1 * b.y + w2 * d.y);
    o.z = (f16)(w0 * a.z + w1 * b.z + w2 * d.z);
    o.w = (f16)(w0 * a.w + w1 * b.w + w2 * d.w);
    *(f16x4*)&A1[(size_t)m * 384 + c] = o;

    const int c2 = l * 2;
    float2 v = *(const float2*)&x_skip[(size_t)m * CSKIP + c2];
    f16x2 s;
    s.x = (f16)v.x;
    s.y = (f16)v.y;
    *(f16x2*)&A1[(size_t)m * 384 + 256 + c2] = s;
}

// ---------------- weight transpose + f16 convert: Wt[n][k] = (f16)W[k][n] ----------------
__global__ __launch_bounds__(256) void wconv_kernel(
    const float* __restrict__ W1, const float* __restrict__ W2,
    f16* __restrict__ W1t, f16* __restrict__ W2t)
{
    const int t = blockIdx.x * 256 + threadIdx.x;
    if (t < 384 * 256) {
        const int k = t >> 8, n = t & 255;
        W1t[n * 384 + k] = (f16)W1[t];
    } else if (t < 384 * 256 + 256 * 256) {
        const int u = t - 384 * 256;
        const int k = u >> 8, n = u & 255;
        W2t[n * 256 + k] = (f16)W2[u];
    }
}

// ---------------- async global->LDS, 16B per lane, linear dest ----------------
__device__ __forceinline__ void gload16(const void* g, void* l)
{
    __builtin_amdgcn_global_load_lds(
        (const __attribute__((address_space(1))) unsigned int*)g,
        (__attribute__((address_space(3))) unsigned int*)l, 16, 0, 0);
}

// ---------------- f16 MFMA GEMM: C[M x 256] = act(A[M x K] @ Bt[256 x K]^T + bias) ----------------
// 128x128 tile, BK=64, 4 waves (2x2), each wave 64x64 via 4x4 16x16x32 frags.
// LDS linear [128][64] f16; XOR swizzle slot^=(row&7) applied on inverse-
// swizzled global SOURCE at staging and on the ds_read address (rule #21).
template <int K, bool OUT_F16>
__global__ __launch_bounds__(256) void gemm_f16_mfma(
    const f16* __restrict__ A, const f16* __restrict__ Bt,
    const float* __restrict__ bias, void* __restrict__ Cout)
{
    __shared__ f16 As[128 * 64];   // 16 KB
    __shared__ f16 Bs[128 * 64];   // 16 KB
    const int tid  = threadIdx.x;
    const int lane = tid & 63;
    const int wid  = tid >> 6;
    const int wr   = wid >> 1, wc = wid & 1;
    const int m0 = blockIdx.x * 128;
    const int n0 = blockIdx.y * 128;

    const int srow_l = lane >> 3;                       // row offset in chunk
    const int kch    = (lane & 7) ^ ((lane >> 3) & 7);  // inverse-swizzled src k-chunk

    f32x4 acc[4][4] = {};

    for (int k0 = 0; k0 < K; k0 += 64) {
#pragma unroll
        for (int r = 0; r < 4; ++r) {
            const int c = (wid << 2) + r;
            const int row = (c << 3) + srow_l;
            gload16(A  + (size_t)(m0 + row) * K + k0 + kch * 8,
                    (char*)As + (c << 10));
            gload16(Bt + (size_t)(n0 + row) * K + k0 + kch * 8,
                    (char*)Bs + (c << 10));
        }
        __syncthreads();

#pragma unroll
        for (int h = 0; h < 2; ++h) {
            f16x8 aF[4], bF[4];
#pragma unroll
            for (int m = 0; m < 4; ++m) {
                const int row  = wr * 64 + m * 16 + (lane & 15);
                const int kg   = (h << 2) + (lane >> 4);
                const int slot = kg ^ (row & 7);
                aF[m] = *(const f16x8*)((const char*)As + row * 128 + slot * 16);
            }
#pragma unroll
            for (int n = 0; n < 4; ++n) {
                const int row  = wc * 64 + n * 16 + (lane & 15);
                const int kg   = (h << 2) + (lane >> 4);
                const int slot = kg ^ (row & 7);
                bF[n] = *(const f16x8*)((const char*)Bs + row * 128 + slot * 16);
            }
#pragma unroll
            for (int m = 0; m < 4; ++m)
#pragma unroll
                for (int n = 0; n < 4; ++n)
                    acc[m][n] = __builtin_amdgcn_mfma_f32_16x16x32_f16(
                        aF[m], bF[n], acc[m][n], 0, 0, 0);
        }
        __syncthreads();
    }

    // epilogue: C/D layout col=lane&15, row=(lane>>4)*4+reg  [m89]
#pragma unroll
    for (int m = 0; m < 4; ++m) {
#pragma unroll
        for (int n = 0; n < 4; ++n) {
            const int col = n0 + wc * 64 + n * 16 + (lane & 15);
            const float bv = bias[col];
#pragma unroll
            for (int r = 0; r < 4; ++r) {
                const int row = m0 + wr * 64 + m * 16 + ((lane >> 4) << 2) + r;
                const float v = fmaxf(acc[m][n][r] + bv, 0.0f);
                if (OUT_F16)
                    ((f16*)Cout)[(size_t)row * 256 + col] = (f16)v;
                else
                    ((float*)Cout)[(size_t)row * 256 + col] = v;
            }
        }
    }
}

// ---------------- tail: pos_skip passthrough + batch_skip as float ----------------
__global__ __launch_bounds__(256) void copy_tail_kernel(
    const float* __restrict__ pos_skip, const int* __restrict__ batch_skip,
    float* __restrict__ out)
{
    const int i = blockIdx.x * 256 + threadIdx.x;
    const int npos = MTOT * 3;
    if (i < npos)               out[i] = pos_skip[i];
    else if (i < npos + MTOT)   out[i] = (float)batch_skip[i - npos];
}

extern "C" void kernel_launch(void* const* d_in, const int* in_sizes, int n_in,
                              void* d_out, int out_size, void* d_ws, size_t ws_size,
                              hipStream_t stream)
{
    const float* x        = (const float*)d_in[0];
    const float* pos      = (const float*)d_in[1];
    const float* x_skip   = (const float*)d_in[2];
    const float* pos_skip = (const float*)d_in[3];
    const float* W1       = (const float*)d_in[4];
    const float* b1       = (const float*)d_in[5];
    const float* W2       = (const float*)d_in[6];
    const float* b2       = (const float*)d_in[7];
    const int*   batch_skip = (const int*)d_in[9];
    float* out = (float*)d_out;

    char* ws = (char*)d_ws;
    int*   idx3 = (int*)ws;                          // 768 KB
    float* w3   = (float*)(ws + (1u << 20));         // 768 KB
    f16*   W1t  = (f16*)(ws + (2u << 20));           // 192 KB
    f16*   W2t  = (f16*)(ws + (2u << 20) + (512u << 10)); // 128 KB
    f16*   A1   = (f16*)(ws + (4u << 20));           // 48 MB
    f16*   h1   = (f16*)(ws + (56u << 20));          // 32 MB

    knn_kernel<<<MTOT / 64, 256, 0, stream>>>(pos, pos_skip, idx3, w3);
    wconv_kernel<<<640, 256, 0, stream>>>(W1, W2, W1t, W2t);
    prep_kernel<<<MTOT / 4, 256, 0, stream>>>(x, x_skip, idx3, w3, A1);

    dim3 g(MTOT / 128, 2);
    gemm_f16_mfma<384, true ><<<g, 256, 0, stream>>>(A1, W1t, b1, h1);
    gemm_f16_mfma<256, false><<<g, 256, 0, stream>>>(h1, W2t, b2, out);

    copy_tail_kernel<<<1024, 256, 0, stream>>>(pos_skip, batch_skip,
                                               out + (size_t)MTOT * CHID);
}